// Round 2
// baseline (160.780 us; speedup 1.0000x reference)
//
#include <hip/hip_runtime.h>
#include <hip/hip_bf16.h>

typedef __hip_bfloat16 bf16;

#define BT 8
#define MM 1023
#define NN 8184

__device__ __forceinline__ float b2f(bf16 v){ return __bfloat162float(v); }

// ---- input segment table (element counts, dict order) ----
// x 523776 | Wf 4096 | bf 64 | W_in 16384 | b_in 256 | W_xp 16896 | W_dt 512
// b_dt 128 | A_log 8192 | D_skip 128 | W_out 8192 | b_out 64 | W_cost 64 | b_cost 1
#define CVT_TOTAL 578753

struct Ptrs { const void* p[14]; };

// ---------------- convert: all inputs -> f32 arena (dtype-adaptive)
__global__ void convert_kernel(Ptrs in, float* __restrict__ dst)
{
    constexpr int cum[15] = {0, 523776, 527872, 527936, 544320, 544576, 561472,
                             561984, 562112, 570304, 570432, 578624, 578688,
                             578752, 578753};
    const int isbf = (((const unsigned*)in.p[8])[0] != 0u);  // A_log[0]==0.0f iff f32
    int idx = blockIdx.x * 256 + threadIdx.x;
    if (idx >= CVT_TOTAL) return;
    int k = 0;
    #pragma unroll
    for (int s = 1; s < 14; ++s) if (idx >= cum[s]) k = s;
    const int local = idx - cum[k];
    dst[idx] = isbf ? b2f(((const bf16*)in.p[k])[local])
                    : ((const float*)in.p[k])[local];
}

// ---------------- prep: W1 = Wf@W_in (f32), b1 = bf@W_in + b_in, A2 = -exp(A_log)*log2e
__global__ void prep_kernel(const float* __restrict__ Wf, const float* __restrict__ bfv,
                            const float* __restrict__ W_in, const float* __restrict__ b_in,
                            const float* __restrict__ A_log,
                            float* __restrict__ W1, float* __restrict__ b1, float* __restrict__ A2)
{
    const int k = blockIdx.x;      // 0..63
    const int c = threadIdx.x;     // 0..255
    float acc = 0.f;
    for (int j = 0; j < 64; ++j)
        acc += Wf[k*64 + j] * W_in[j*256 + c];
    W1[k*256 + c] = acc;
    if (k == 0) {
        float a2 = b_in[c];
        for (int j = 0; j < 64; ++j)
            a2 += bfv[j] * W_in[j*256 + c];
        b1[c] = a2;
    }
    const int id = k*256 + c;
    if (id < 128*64)
        A2[id] = -__expf(A_log[id]) * 1.44269504f;
}

// ---------------- node features: xi -> dt, P = dt*xi, B. Weights in registers.
// grid (64, 8), block 256 = 2 slots x 128 threads; slot handles 8 sequential nodes.
__global__ __launch_bounds__(256) void node_kernel(
        const float* __restrict__ x, const float* __restrict__ W_xp,
        const float* __restrict__ W_dt, const float* __restrict__ b_dt,
        const float* __restrict__ W1, const float* __restrict__ b1,
        float* __restrict__ dtg, float* __restrict__ Pg, float* __restrict__ Bv)
{
    __shared__ __align__(16) float buf[128*68];   // staging for reg loads (reused)
    __shared__ __align__(16) float xrow[2][68];
    __shared__ __align__(16) float xiS[2][132];
    __shared__ float red[2][2][4];
    __shared__ float Bpart[2][66];

    const int tid  = threadIdx.x;
    const int slot = tid >> 7;
    const int e    = tid & 127;
    const int t    = blockIdx.y;
    const int s64  = e & 63, h = e >> 6;

    // stage W1 cols 0..127 transposed -> registers (thread e owns column e)
    for (int idx = tid; idx < 8192; idx += 256) {
        int k = idx >> 7, c = idx & 127;
        buf[c*68 + k] = W1[k*256 + c];
    }
    __syncthreads();
    float w1c[64];
    #pragma unroll
    for (int k = 0; k < 64; k += 4) {
        float4 v = *(const float4*)&buf[e*68 + k];
        w1c[k] = v.x; w1c[k+1] = v.y; w1c[k+2] = v.z; w1c[k+3] = v.w;
    }
    __syncthreads();
    // stage W_xp[:,4:68] transposed [s][j] -> registers (thread owns half-column)
    for (int idx = tid; idx < 8192; idx += 256) {
        int j = idx >> 6, s = idx & 63;
        buf[s*132 + j] = W_xp[j*132 + 4 + s];
    }
    __syncthreads();
    float wb[64];
    #pragma unroll
    for (int k = 0; k < 64; k += 4) {
        float4 v = *(const float4*)&buf[s64*132 + h*64 + k];
        wb[k] = v.x; wb[k+1] = v.y; wb[k+2] = v.z; wb[k+3] = v.w;
    }
    float wxp4[4], wdt4[4];
    #pragma unroll
    for (int r = 0; r < 4; ++r) wxp4[r] = W_xp[e*132 + r];
    #pragma unroll
    for (int r = 0; r < 4; ++r) wdt4[r] = W_dt[r*128 + e];
    const float b1e  = b1[e];
    const float bdte = b_dt[e];

    for (int q = 0; q < 8; ++q) {
        int i = blockIdx.x*16 + slot*8 + q;
        if (i > 1022) i = 1022;               // duplicate store of node 1022 is benign
        const int g = t*MM + i;
        __syncthreads();                       // protect xrow/xiS from prior-iter readers
        if (e < 64) xrow[slot][e] = x[g*64 + e];
        __syncthreads();
        // xz (col e) and silu
        float acc = b1e;
        #pragma unroll
        for (int k = 0; k < 64; k += 4) {
            float4 xv = *(const float4*)&xrow[slot][k];
            acc += xv.x*w1c[k] + xv.y*w1c[k+1] + xv.z*w1c[k+2] + xv.w*w1c[k+3];
        }
        float xi_e = acc / (1.f + __expf(-acc));
        xiS[slot][e] = xi_e;
        // dbc[:,0:4] via wave reduction
        float p0 = xi_e*wxp4[0], p1 = xi_e*wxp4[1], p2 = xi_e*wxp4[2], p3 = xi_e*wxp4[3];
        #pragma unroll
        for (int off = 32; off; off >>= 1) {
            p0 += __shfl_down(p0, off);
            p1 += __shfl_down(p1, off);
            p2 += __shfl_down(p2, off);
            p3 += __shfl_down(p3, off);
        }
        const int w = (tid >> 6) & 1;
        if ((tid & 63) == 0) {
            red[slot][w][0] = p0; red[slot][w][1] = p1;
            red[slot][w][2] = p2; red[slot][w][3] = p3;
        }
        __syncthreads();
        float d0 = red[slot][0][0] + red[slot][1][0];
        float d1 = red[slot][0][1] + red[slot][1][1];
        float d2 = red[slot][0][2] + red[slot][1][2];
        float d3 = red[slot][0][3] + red[slot][1][3];
        float pre = bdte + d0*wdt4[0] + d1*wdt4[1] + d2*wdt4[2] + d3*wdt4[3];
        float dt  = fmaxf(pre, 0.f) + log1pf(__expf(-fabsf(pre)));   // softplus
        dtg[g*128 + e] = dt;
        Pg[g*128 + e]  = dt * xi_e;
        // B (col s64, half h)
        float accB = 0.f;
        #pragma unroll
        for (int k = 0; k < 64; k += 4) {
            float4 xv = *(const float4*)&xiS[slot][h*64 + k];
            accB += xv.x*wb[k] + xv.y*wb[k+1] + xv.z*wb[k+2] + xv.w*wb[k+3];
        }
        if (h == 1) Bpart[slot][s64] = accB;
        __syncthreads();
        if (h == 0) Bv[g*64 + s64] = accB + Bpart[slot][s64];
    }
}

// ---------------- roots: z, C, xi at the 8 tree roots
__global__ void root_kernel(const float* __restrict__ x, const float* __restrict__ W_xp,
                            const float* __restrict__ W1, const float* __restrict__ b1,
                            float* __restrict__ rootC, float* __restrict__ rootXi,
                            float* __restrict__ rootZ)
{
    const int t = blockIdx.x, e = threadIdx.x;   // 128 threads
    __shared__ float xr[64];
    __shared__ float xiL[132];
    const int g = t*MM;
    if (e < 64) xr[e] = x[g*64 + e];
    __syncthreads();
    float a0 = b1[e], a1 = b1[e + 128];
    for (int k = 0; k < 64; ++k) {
        float xv = xr[k];
        a0 += xv * W1[k*256 + e];
        a1 += xv * W1[k*256 + e + 128];
    }
    float xi_e = a0 / (1.f + __expf(-a0));
    xiL[e] = xi_e;
    rootXi[t*128 + e] = xi_e;
    rootZ[t*128 + e]  = a1;
    __syncthreads();
    if (e < 64) {
        float ac = 0.f;
        for (int j = 0; j < 128; ++j)
            ac += xiL[j] * W_xp[j*132 + 68 + e];
        rootC[t*64 + e] = ac;
    }
}

// ---------------- accumulate: per node, T = sum of ancestor dt; inner exp loop over s.
// grid (64, 8), block 256 = 2 slots x 128; block partial -> ypart (deterministic)
__global__ __launch_bounds__(256) void accum_kernel(
        const float* __restrict__ A2g, const float* __restrict__ rootC,
        const float* __restrict__ dtg, const float* __restrict__ Pg,
        const float* __restrict__ Bv, float* __restrict__ ypart)
{
    __shared__ __align__(16) float A2l[128][68];
    __shared__ __align__(16) float CBl[2][68];
    __shared__ float rootCs[64];
    __shared__ float comb[132];
    const int tid = threadIdx.x, slot = tid >> 7, e = tid & 127;
    const int t = blockIdx.y, bx = blockIdx.x;

    for (int idx = tid; idx < 8192; idx += 256)
        A2l[idx >> 6][idx & 63] = A2g[idx];
    if (tid < 64) rootCs[tid] = rootC[t*64 + tid];
    __syncthreads();
    float a2r[64];
    #pragma unroll
    for (int k = 0; k < 64; k += 4) {
        float4 v = *(const float4*)&A2l[e][k];
        a2r[k] = v.x; a2r[k+1] = v.y; a2r[k+2] = v.z; a2r[k+3] = v.w;
    }
    float acc = 0.f;
    for (int q = 0; q < 8; ++q) {
        int i = bx*16 + slot*8 + q;
        bool valid = (i < 1023);
        int ic = valid ? i : 1022;
        const int g = t*MM + ic;
        float T = 0.f;
        int ii = ic;
        while (ii > 0) { ii = (ii - 1) >> 1; T += dtg[(t*MM + ii)*128 + e]; }
        float Pe = Pg[g*128 + e];
        __syncthreads();                        // prior CB reads complete
        if (e < 64) CBl[slot][e] = rootCs[e] * Bv[g*64 + e];
        __syncthreads();                        // CB ready
        float acn = 0.f;
        #pragma unroll
        for (int s = 0; s < 64; s += 4) {
            float4 cb = *(const float4*)&CBl[slot][s];
            acn += cb.x * exp2f(a2r[s]   * T);
            acn += cb.y * exp2f(a2r[s+1] * T);
            acn += cb.z * exp2f(a2r[s+2] * T);
            acn += cb.w * exp2f(a2r[s+3] * T);
        }
        if (valid) acc += Pe * acn;
    }
    if (slot == 1) comb[e] = acc;
    __syncthreads();
    if (slot == 0) ypart[(t*64 + bx)*128 + e] = acc + comb[e];
}

// ---------------- epilogue: reduce partials, gate with silu(z), W_out, W_cost
__global__ void epi_kernel(const float* __restrict__ ypart, const float* __restrict__ rootXi,
                           const float* __restrict__ rootZ,
                           const float* __restrict__ D_skip, const float* __restrict__ W_out,
                           const float* __restrict__ b_out, const float* __restrict__ W_cost,
                           const float* __restrict__ b_cost,
                           const void* __restrict__ A_log_raw, void* __restrict__ out)
{
    const int t = blockIdx.x, j = threadIdx.x;   // 64 threads
    __shared__ float yv[128];
    for (int hh = 0; hh < 2; ++hh) {
        int e = j + 64*hh;
        float ys = 0.f;
        for (int b = 0; b < 64; ++b) ys += ypart[(t*64 + b)*128 + e];
        float zr = rootZ[t*128 + e];
        float sz = zr / (1.f + __expf(-zr));
        yv[e] = (ys + D_skip[e] * rootXi[t*128 + e]) * sz;
    }
    __syncthreads();
    float o = b_out[j];
    for (int ee = 0; ee < 128; ++ee)
        o += yv[ee] * W_out[ee*64 + j];
    float r = o * W_cost[j];
    #pragma unroll
    for (int off = 32; off; off >>= 1) r += __shfl_down(r, off);
    if (j == 0) {
        float v = r + b_cost[0];
        const int isbf = (((const unsigned*)A_log_raw)[0] != 0u);
        if (isbf) ((bf16*)out)[t] = __float2bfloat16(v);
        else      ((float*)out)[t] = v;
    }
}

extern "C" void kernel_launch(void* const* d_in, const int* in_sizes, int n_in,
                              void* d_out, int out_size, void* d_ws, size_t ws_size,
                              hipStream_t stream) {
    Ptrs ptrs;
    for (int i = 0; i < 14; ++i) ptrs.p[i] = d_in[i];

    float* arena = (float*)d_ws;
    float* xF      = arena + 0;
    float* WfF     = arena + 523776;
    float* bfF     = arena + 527872;
    float* W_inF   = arena + 527936;
    float* b_inF   = arena + 544320;
    float* W_xpF   = arena + 544576;
    float* W_dtF   = arena + 561472;
    float* b_dtF   = arena + 561984;
    float* A_logF  = arena + 562112;
    float* D_skipF = arena + 570304;
    float* W_outF  = arena + 570432;
    float* b_outF  = arena + 578624;
    float* W_costF = arena + 578688;
    float* b_costF = arena + 578752;

    float* ws2    = arena + 578816;
    float* W1     = ws2;                 // 16384
    float* b1     = W1 + 16384;          // 256
    float* A2     = b1 + 256;            // 8192
    float* dtg    = A2 + 8192;           // 1047552
    float* Pg     = dtg + 1047552;       // 1047552
    float* Bv     = Pg + 1047552;        // 523776
    float* rootC  = Bv + 523776;         // 512
    float* rootXi = rootC + 512;         // 1024
    float* rootZ  = rootXi + 1024;       // 1024
    float* ypart  = rootZ + 1024;        // 65536   (total ~12.6 MB)

    convert_kernel<<<dim3((CVT_TOTAL + 255) / 256), 256, 0, stream>>>(ptrs, arena);
    prep_kernel<<<dim3(64), 256, 0, stream>>>(WfF, bfF, W_inF, b_inF, A_logF, W1, b1, A2);
    node_kernel<<<dim3(64, 8), 256, 0, stream>>>(xF, W_xpF, W_dtF, b_dtF, W1, b1, dtg, Pg, Bv);
    root_kernel<<<dim3(8), 128, 0, stream>>>(xF, W_xpF, W1, b1, rootC, rootXi, rootZ);
    accum_kernel<<<dim3(64, 8), 256, 0, stream>>>(A2, rootC, dtg, Pg, Bv, ypart);
    epi_kernel<<<dim3(8), 64, 0, stream>>>(ypart, rootXi, rootZ, D_skipF, W_outF, b_outF,
                                           W_costF, b_costF, d_in[8], d_out);
}